// Round 7
// baseline (21.864 us; speedup 1.0000x reference)
//
#include <hip/hip_runtime.h>
#include <hip/hip_bf16.h>
#include <math.h>

// Problem constants (fixed by the reference setup_inputs)
#define NROWS 2048
#define KROWS 256
#define DDIM  512

typedef __attribute__((ext_vector_type(8))) short short8;
typedef __attribute__((ext_vector_type(4))) float f32x4;

// Workspace layout (bytes) — bf16 tensors stored in MFMA-fragment order:
//   chunk index ((tile*16 + s)*64 + kg*16 + r) holds
//   T[tile*16 + r][s*32 + kg*8 .. +8] as short8, so a wave load at
//   base + s*64chunks + lane is 1KB coalesced and fragment-ready.
//   PT [K/16][16][64] short8 : @0        (262144 B)
//   AT [K/16][16][64] short8 : @262144   (262144 B)
//   SC [K] float4            : @524288   (4096 B)   {p2, pa, na, kc}
#define AB_BYTE   262144
#define SC_FOFF   131072   // float offset

__device__ inline unsigned short f2bf(float f) {
    // round-to-nearest-even fp32 -> bf16 (inputs are finite)
    unsigned u = __float_as_uint(f);
    u += 0x7fffu + ((u >> 16) & 1u);
    return (unsigned short)(u >> 16);
}

__device__ inline float wave_reduce_sum(float v) {
    #pragma unroll
    for (int off = 32; off > 0; off >>= 1)
        v += __shfl_xor(v, off, 64);
    return v;
}

// Slim prep: 64 blocks x 256 threads, one k per wave.
// expmap0 + conformal prep -> bf16 P/A in fragment order + SC scalars.
__global__ __launch_bounds__(256) void hmlr_prep(
        const float* __restrict__ a_vals,
        const float* __restrict__ p_vals,
        float* __restrict__ ws) {
    const int tid  = threadIdx.x;
    const int w    = tid >> 6;
    const int lane = tid & 63;
    const int k    = blockIdx.x * 4 + w;  // 0..255

    const float4* pv4 = (const float4*)(p_vals) + k * (DDIM / 4) + lane * 2;
    const float4* av4 = (const float4*)(a_vals) + k * (DDIM / 4) + lane * 2;
    float4 p0 = pv4[0], p1 = pv4[1];
    float4 a0 = av4[0], a1 = av4[1];

    float pn2 = p0.x*p0.x + p0.y*p0.y + p0.z*p0.z + p0.w*p0.w
              + p1.x*p1.x + p1.y*p1.y + p1.z*p1.z + p1.w*p1.w;
    float an2 = a0.x*a0.x + a0.y*a0.y + a0.z*a0.z + a0.w*a0.w
              + a1.x*a1.x + a1.y*a1.y + a1.z*a1.z + a1.w*a1.w;
    float pa0 = p0.x*a0.x + p0.y*a0.y + p0.z*a0.z + p0.w*a0.w
              + p1.x*a1.x + p1.y*a1.y + p1.z*a1.z + p1.w*a1.w;

    pn2 = wave_reduce_sum(pn2);
    an2 = wave_reduce_sum(an2);
    pa0 = wave_reduce_sum(pa0);

    // expmap0 with c = 1: p = tanh(clamp(||u||,15)) * u / ||u||
    float u     = fmaxf(sqrtf(pn2), 1e-5f);
    float t     = tanhf(fminf(u, 15.0f));
    float scale = t / u;
    float p2    = scale * scale * pn2;       // ||p_poincare||^2
    float conf  = 1.0f - p2;                 // conformal factor (c=1)
    float na    = fmaxf(conf * sqrtf(an2), 1e-7f);  // max(||a_poincare||, 1e-7)
    float pa    = scale * conf * pa0;        // dot(p_poincare, a_poincare)
    float lam   = 2.0f / (1.0f - fminf(p2, 0.9999f)); // 1/c - 1e-4 = 0.9999
    float kc    = lam * na;                  // / sqrt(c) = 1

    float pf[8] = { scale*p0.x, scale*p0.y, scale*p0.z, scale*p0.w,
                    scale*p1.x, scale*p1.y, scale*p1.z, scale*p1.w };
    float af[8] = { conf*a0.x, conf*a0.y, conf*a0.z, conf*a0.w,
                    conf*a1.x, conf*a1.y, conf*a1.z, conf*a1.w };
    short8 pu, au;
    #pragma unroll
    for (int j = 0; j < 8; ++j) {
        pu[j] = (short)f2bf(pf[j]);
        au[j] = (short)f2bf(af[j]);
    }
    // fragment-order scatter: s = lane>>2, kg = lane&3, r = k&15
    short8* PT8 = (short8*)ws;
    short8* AT8 = (short8*)((char*)ws + AB_BYTE);
    const int ci = (((k >> 4) * 16 + (lane >> 2)) * 64) + (lane & 3) * 16 + (k & 15);
    PT8[ci] = pu;
    AT8[ci] = au;
    if (lane == 0)
        ((float4*)(ws + SC_FOFF))[k] = make_float4(p2, pa, na, kc);
}

// Main MFMA kernel: one 16(M) x 16(class) tile per wave.
// Block = 4 waves with the SAME ct (identical P/A fragment addresses ->
// L1 broadcast, P/A L2 traffic /4) and 4 consecutive mt.
// X loaded fp32 + converted in-register; y2 computed on the fly via
// kg-butterfly. 48 coalesced loads preloaded, 4 independent MFMA chains,
// fused analytic epilogue. No LDS, no barriers.
// C/D: col = lane&15 (class), row = (lane>>4)*4 + reg (m)   [m89 verified]
__global__ __launch_bounds__(256, 2) void hmlr_main(
        const float* __restrict__ x,
        const float* __restrict__ ws,
        float* __restrict__ out) {
    const int lane = threadIdx.x & 63;
    const int w    = threadIdx.x >> 6;
    const int ct   = blockIdx.x & 15;             // 0..15
    const int mt   = (blockIdx.x >> 4) * 4 + w;   // 0..127
    const int m0   = mt * 16;
    const int c0   = ct * 16;
    const int row  = lane & 15;
    const int kg   = lane >> 4;

    const short8* PT8 = (const short8*)ws;
    const short8* AT8 = (const short8*)((const char*)ws + AB_BYTE);
    const float*  SC  = ws + SC_FOFF;

    const short8* pt = PT8 + ct * 16 * 64 + lane;
    const short8* at = AT8 + ct * 16 * 64 + lane;

    // X: fp32 load + in-register bf16 convert + y2 on the fly.
    // Lane (row,kg) covers X[m0+row][kg*8 + 32*s .. +7] -> 128 elems/lane;
    // row's 512 elems live on lanes {row, row+16, row+32, row+48}.
    short8 xv[16];
    float  ss = 0.0f;
    const float* xr = x + (m0 + row) * DDIM + kg * 8;
    #pragma unroll
    for (int s = 0; s < 16; ++s) {
        float4 v0 = *(const float4*)(xr + s * 32);
        float4 v1 = *(const float4*)(xr + s * 32 + 4);
        ss += v0.x*v0.x + v0.y*v0.y + v0.z*v0.z + v0.w*v0.w
            + v1.x*v1.x + v1.y*v1.y + v1.z*v1.z + v1.w*v1.w;
        short8 xu;
        xu[0] = (short)f2bf(v0.x); xu[1] = (short)f2bf(v0.y);
        xu[2] = (short)f2bf(v0.z); xu[3] = (short)f2bf(v0.w);
        xu[4] = (short)f2bf(v1.x); xu[5] = (short)f2bf(v1.y);
        xu[6] = (short)f2bf(v1.z); xu[7] = (short)f2bf(v1.w);
        xv[s] = xu;
    }
    // butterfly over kg: every lane ends with y2[m0 + row]
    ss += __shfl_xor(ss, 16, 64);
    ss += __shfl_xor(ss, 32, 64);

    // P/A fragment preload (coalesced 1KB per load; same addresses on all
    // 4 waves of the block -> L1 broadcast)
    short8 pv[16], av[16];
    #pragma unroll
    for (int s = 0; s < 16; ++s) pv[s] = pt[s * 64];
    #pragma unroll
    for (int s = 0; s < 16; ++s) av[s] = at[s * 64];

    // MFMA burst: 4 independent chains of depth 8
    f32x4 aP[2] = {{0.f,0.f,0.f,0.f},{0.f,0.f,0.f,0.f}};
    f32x4 aA[2] = {{0.f,0.f,0.f,0.f},{0.f,0.f,0.f,0.f}};
    #pragma unroll
    for (int s = 0; s < 16; ++s) {
        aP[s & 1] = __builtin_amdgcn_mfma_f32_16x16x32_bf16(xv[s], pv[s], aP[s & 1], 0, 0, 0);
        aA[s & 1] = __builtin_amdgcn_mfma_f32_16x16x32_bf16(xv[s], av[s], aA[s & 1], 0, 0, 0);
    }
    f32x4 accP = aP[0] + aP[1];
    f32x4 accA = aA[0] + aA[1];

    // ---- fused epilogue ----
    const int c = c0 + row;
    f32x4 sc = *(const f32x4*)(SC + 4 * c);
    const float p2 = sc[0], pa = sc[1], na = sc[2], kc = sc[3];
    #pragma unroll
    for (int j = 0; j < 4; ++j) {
        const int m     = m0 + kg * 4 + j;
        const float y2n = __shfl(ss, kg * 4 + j, 64);  // y2 of row kg*4+j lives there
        const float xpv = accP[j];
        const float xav = accA[j];
        // mobius_addition_batch(-p, x): xy = -xp
        const float alpha = 1.0f - 2.0f * xpv + y2n;       // 1 + 2c*xy + c*y2
        const float beta  = 1.0f - p2;                     // 1 - c*||p||^2
        const float gam   = 1.0f - 2.0f * xpv + p2 * y2n;  // denom
        const float gi    = 1.0f / (gam + 1e-5f);
        const float num   = 2.0f * (beta * xav - alpha * pa) * gi;
        const float mob2  = (alpha*alpha*p2 + beta*beta*y2n
                             - 2.0f*alpha*beta*xpv) * gi * gi;
        const float den   = na * (1.0f - mob2);
        const float z     = num / den;
        // arsinh(z) = log(max(z + sqrt(1+z^2), 1e-5))
        out[m * KROWS + c] = kc * logf(fmaxf(z + sqrtf(1.0f + z * z), 1e-5f));
    }
}

extern "C" void kernel_launch(void* const* d_in, const int* in_sizes, int n_in,
                              void* d_out, int out_size, void* d_ws, size_t ws_size,
                              hipStream_t stream) {
    (void)in_sizes; (void)n_in; (void)out_size; (void)ws_size;
    const float* x      = (const float*)d_in[0];
    const float* a_vals = (const float*)d_in[1];
    const float* p_vals = (const float*)d_in[2];
    float* ws  = (float*)d_ws;
    float* out = (float*)d_out;

    // prep: 64 blocks (one k per wave) — P/A/SC only
    hmlr_prep<<<64, 256, 0, stream>>>(a_vals, p_vals, ws);
    // main: 512 blocks = 16 ct x 32 mt-groups (4 mt per block)
    hmlr_main<<<512, 256, 0, stream>>>(x, ws, out);
}

// Round 8
// 16.144 us; speedup vs baseline: 1.3543x; 1.3543x over previous
//
#include <hip/hip_runtime.h>
#include <hip/hip_bf16.h>
#include <math.h>

// Problem constants (fixed by the reference setup_inputs)
#define NROWS 2048
#define KROWS 256
#define DDIM  512

typedef __attribute__((ext_vector_type(8))) short short8;
typedef __attribute__((ext_vector_type(4))) float f32x4;

// Workspace layout (bytes) — bf16 tensors stored in MFMA-fragment order:
//   chunk index ((tile*16 + s)*64 + kg*16 + r) holds
//   T[tile*16 + r][s*32 + kg*8 .. +8] as short8, so a wave load at
//   base + s*64chunks + lane is 1KB coalesced and fragment-ready.
//   PT [K/16][16][64] short8 : @0        (262144 B)
//   AT [K/16][16][64] short8 : @262144   (262144 B)
//   SC [K] float4            : @524288   (4096 B)   {p2, pa, na, kc}
//   Y2 [N] float             : @528384   (8192 B)
//   XT [N/16][16][64] short8 : @536576   (2097152 B)  (only if ws_size allows)
#define AB_BYTE   262144
#define SC_FOFF   131072   // float offset
#define Y2_FOFF   132096   // float offset
#define XB_BYTE   536576
#define WS_NEEDED (536576 + 2097152)

__device__ inline unsigned short f2bf(float f) {
    // round-to-nearest-even fp32 -> bf16 (inputs are finite)
    unsigned u = __float_as_uint(f);
    u += 0x7fffu + ((u >> 16) & 1u);
    return (unsigned short)(u >> 16);
}

__device__ inline float wave_reduce_sum(float v) {
    #pragma unroll
    for (int off = 32; off > 0; off >>= 1)
        v += __shfl_xor(v, off, 64);
    return v;
}

// One wave per k (blocks 0..63, 4 k/block) or per x-row (blocks 64..575, 4 rows/block).
template <bool XBWS>
__global__ __launch_bounds__(256) void hmlr_prep(
        const float* __restrict__ x,
        const float* __restrict__ a_vals,
        const float* __restrict__ p_vals,
        float* __restrict__ ws) {
    const int tid  = threadIdx.x;
    const int w    = tid >> 6;
    const int lane = tid & 63;
    const int bid  = blockIdx.x;

    if (bid < 64) {
        const int k = bid * 4 + w;  // 0..255
        const float4* pv4 = (const float4*)(p_vals) + k * (DDIM / 4) + lane * 2;
        const float4* av4 = (const float4*)(a_vals) + k * (DDIM / 4) + lane * 2;
        float4 p0 = pv4[0], p1 = pv4[1];
        float4 a0 = av4[0], a1 = av4[1];

        float pn2 = p0.x*p0.x + p0.y*p0.y + p0.z*p0.z + p0.w*p0.w
                  + p1.x*p1.x + p1.y*p1.y + p1.z*p1.z + p1.w*p1.w;
        float an2 = a0.x*a0.x + a0.y*a0.y + a0.z*a0.z + a0.w*a0.w
                  + a1.x*a1.x + a1.y*a1.y + a1.z*a1.z + a1.w*a1.w;
        float pa0 = p0.x*a0.x + p0.y*a0.y + p0.z*a0.z + p0.w*a0.w
                  + p1.x*a1.x + p1.y*a1.y + p1.z*a1.z + p1.w*a1.w;

        pn2 = wave_reduce_sum(pn2);
        an2 = wave_reduce_sum(an2);
        pa0 = wave_reduce_sum(pa0);

        // expmap0 with c = 1: p = tanh(clamp(||u||,15)) * u / ||u||
        float u     = fmaxf(sqrtf(pn2), 1e-5f);
        float t     = tanhf(fminf(u, 15.0f));
        float scale = t / u;
        float p2    = scale * scale * pn2;       // ||p_poincare||^2
        float conf  = 1.0f - p2;                 // conformal factor (c=1)
        float na    = fmaxf(conf * sqrtf(an2), 1e-7f);  // max(||a_poincare||, 1e-7)
        float pa    = scale * conf * pa0;        // dot(p_poincare, a_poincare)
        float lam   = 2.0f / (1.0f - fminf(p2, 0.9999f)); // 1/c - 1e-4 = 0.9999
        float kc    = lam * na;                  // / sqrt(c) = 1

        float pf[8] = { scale*p0.x, scale*p0.y, scale*p0.z, scale*p0.w,
                        scale*p1.x, scale*p1.y, scale*p1.z, scale*p1.w };
        float af[8] = { conf*a0.x, conf*a0.y, conf*a0.z, conf*a0.w,
                        conf*a1.x, conf*a1.y, conf*a1.z, conf*a1.w };
        short8 pu, au;
        #pragma unroll
        for (int j = 0; j < 8; ++j) {
            pu[j] = (short)f2bf(pf[j]);
            au[j] = (short)f2bf(af[j]);
        }
        // fragment-order scatter: s = lane>>2, kg = lane&3, r = k&15
        short8* PT8 = (short8*)ws;
        short8* AT8 = (short8*)((char*)ws + AB_BYTE);
        const int ci = (((k >> 4) * 16 + (lane >> 2)) * 64) + (lane & 3) * 16 + (k & 15);
        PT8[ci] = pu;
        AT8[ci] = au;
        if (lane == 0)
            ((float4*)(ws + SC_FOFF))[k] = make_float4(p2, pa, na, kc);
    } else {
        const int row = (bid - 64) * 4 + w;  // 0..2047
        const float4* xv4 = (const float4*)(x) + row * (DDIM / 4) + lane * 2;
        float4 x0 = xv4[0], x1 = xv4[1];
        float s = x0.x*x0.x + x0.y*x0.y + x0.z*x0.z + x0.w*x0.w
                + x1.x*x1.x + x1.y*x1.y + x1.z*x1.z + x1.w*x1.w;
        s = wave_reduce_sum(s);
        if (lane == 0) ws[Y2_FOFF + row] = s;
        if (XBWS) {
            short8* XT8 = (short8*)((char*)ws + XB_BYTE);
            short8 xu;
            xu[0] = (short)f2bf(x0.x); xu[1] = (short)f2bf(x0.y);
            xu[2] = (short)f2bf(x0.z); xu[3] = (short)f2bf(x0.w);
            xu[4] = (short)f2bf(x1.x); xu[5] = (short)f2bf(x1.y);
            xu[6] = (short)f2bf(x1.z); xu[7] = (short)f2bf(x1.w);
            const int ci = (((row >> 4) * 16 + (lane >> 2)) * 64) + (lane & 3) * 16 + (row & 15);
            XT8[ci] = xu;
        }
    }
}

// D-split main kernel: each 16(M)x16(class) tile computed by a PAIR of waves,
// each summing half of D (8 MFMA K-steps), combined via LDS, epilogue split.
// Grid: 1024 blocks x 256 thr = 4096 waves (4 waves/SIMD, 2x R5 concurrency).
// Block = 1 mt x {2 ct x 2 half}; the two ct-waves of a half share X-frag
// addresses (L1 broadcast). bid = mt*8 + cp -> each XCD sees a fixed ct-pair
// (64KB P/A) + all XT (2MB): working set fits the XCD's private L2.
// C/D: col = lane&15 (class), row = (lane>>4)*4 + reg (m)   [m89 verified]
template <bool XBWS>
__global__ __launch_bounds__(256, 4) void hmlr_main_split(
        const float* __restrict__ x,
        const float* __restrict__ ws,
        float* __restrict__ out) {
    __shared__ f32x4 ex[4][2][64];   // per-wave accP/accA exchange (8KB)
    __shared__ float exs[4][64];     // y2-half exchange (fallback path only)

    const int lane = threadIdx.x & 63;
    const int w    = threadIdx.x >> 6;
    const int ci   = w >> 1;                  // which ct of the pair
    const int h    = w & 1;                   // D-half
    const int mt   = blockIdx.x >> 3;         // 0..127
    const int cp   = blockIdx.x & 7;          // ct-pair 0..7
    const int ct   = cp * 2 + ci;             // 0..15
    const int m0   = mt * 16;
    const int c0   = ct * 16;
    const int row  = lane & 15;
    const int kg   = lane >> 4;

    const short8* PT8 = (const short8*)ws;
    const short8* AT8 = (const short8*)((const char*)ws + AB_BYTE);
    const float*  SC  = ws + SC_FOFF;
    const float*  Y2  = ws + Y2_FOFF;

    const short8* pt = PT8 + ct * 16 * 64 + h * 8 * 64 + lane;
    const short8* at = AT8 + ct * 16 * 64 + h * 8 * 64 + lane;

    // ---- load this wave's half of the K-dim (8 X + 8 P + 8 A fragments) ----
    short8 xv[8];
    float  ss = 0.0f;   // fallback-path partial y2
    if (XBWS) {
        const short8* xt = (const short8*)((const char*)ws + XB_BYTE)
                           + mt * 16 * 64 + h * 8 * 64 + lane;
        #pragma unroll
        for (int s = 0; s < 8; ++s) xv[s] = xt[s * 64];
    } else {
        const float* xr = x + (m0 + row) * DDIM + h * 256 + kg * 8;
        #pragma unroll
        for (int s = 0; s < 8; ++s) {
            float4 v0 = *(const float4*)(xr + s * 32);
            float4 v1 = *(const float4*)(xr + s * 32 + 4);
            ss += v0.x*v0.x + v0.y*v0.y + v0.z*v0.z + v0.w*v0.w
                + v1.x*v1.x + v1.y*v1.y + v1.z*v1.z + v1.w*v1.w;
            short8 xu;
            xu[0] = (short)f2bf(v0.x); xu[1] = (short)f2bf(v0.y);
            xu[2] = (short)f2bf(v0.z); xu[3] = (short)f2bf(v0.w);
            xu[4] = (short)f2bf(v1.x); xu[5] = (short)f2bf(v1.y);
            xu[6] = (short)f2bf(v1.z); xu[7] = (short)f2bf(v1.w);
            xv[s] = xu;
        }
        ss += __shfl_xor(ss, 16, 64);
        ss += __shfl_xor(ss, 32, 64);   // half-y2 of row (all lanes)
    }
    short8 pv[8], av[8];
    #pragma unroll
    for (int s = 0; s < 8; ++s) pv[s] = pt[s * 64];
    #pragma unroll
    for (int s = 0; s < 8; ++s) av[s] = at[s * 64];

    // ---- MFMA: 4 independent chains of depth 4 ----
    f32x4 aP[2] = {{0.f,0.f,0.f,0.f},{0.f,0.f,0.f,0.f}};
    f32x4 aA[2] = {{0.f,0.f,0.f,0.f},{0.f,0.f,0.f,0.f}};
    #pragma unroll
    for (int s = 0; s < 8; ++s) {
        aP[s & 1] = __builtin_amdgcn_mfma_f32_16x16x32_bf16(xv[s], pv[s], aP[s & 1], 0, 0, 0);
        aA[s & 1] = __builtin_amdgcn_mfma_f32_16x16x32_bf16(xv[s], av[s], aA[s & 1], 0, 0, 0);
    }
    f32x4 accP = aP[0] + aP[1];
    f32x4 accA = aA[0] + aA[1];

    // ---- combine the two D-halves via LDS ----
    ex[w][0][lane] = accP;
    ex[w][1][lane] = accA;
    if (!XBWS) exs[w][lane] = ss;
    __syncthreads();
    const int pw = w ^ 1;  // partner: same ct, other half
    accP += ex[pw][0][lane];
    accA += ex[pw][1][lane];
    float ssf = XBWS ? 0.0f : (ss + exs[pw][lane]);

    // ---- fused epilogue: this wave writes rows j = 2h, 2h+1 ----
    const int c = c0 + row;
    f32x4 sc = *(const f32x4*)(SC + 4 * c);
    const float p2 = sc[0], pa = sc[1], na = sc[2], kc = sc[3];
    #pragma unroll
    for (int jj = 0; jj < 2; ++jj) {
        const int j     = 2 * h + jj;
        const int m     = m0 + kg * 4 + j;
        const float y2n = XBWS ? Y2[m] : __shfl(ssf, kg * 4 + j, 64);
        const float xpv = accP[j];
        const float xav = accA[j];
        // mobius_addition_batch(-p, x): xy = -xp
        const float alpha = 1.0f - 2.0f * xpv + y2n;       // 1 + 2c*xy + c*y2
        const float beta  = 1.0f - p2;                     // 1 - c*||p||^2
        const float gam   = 1.0f - 2.0f * xpv + p2 * y2n;  // denom
        const float gi    = __builtin_amdgcn_rcpf(gam + 1e-5f);
        const float num   = 2.0f * (beta * xav - alpha * pa) * gi;
        const float mob2  = (alpha*alpha*p2 + beta*beta*y2n
                             - 2.0f*alpha*beta*xpv) * gi * gi;
        const float den   = na * (1.0f - mob2);
        const float z     = num * __builtin_amdgcn_rcpf(den);
        // arsinh(z) = log(max(z + sqrt(1+z^2), 1e-5))
        const float arg   = fmaxf(z + __builtin_amdgcn_sqrtf(1.0f + z * z), 1e-5f);
        out[m * KROWS + c] = kc * __logf(arg);
    }
}

extern "C" void kernel_launch(void* const* d_in, const int* in_sizes, int n_in,
                              void* d_out, int out_size, void* d_ws, size_t ws_size,
                              hipStream_t stream) {
    (void)in_sizes; (void)n_in; (void)out_size;
    const float* x      = (const float*)d_in[0];
    const float* a_vals = (const float*)d_in[1];
    const float* p_vals = (const float*)d_in[2];
    float* ws  = (float*)d_ws;
    float* out = (float*)d_out;

    if (ws_size >= (size_t)WS_NEEDED) {
        hmlr_prep<true><<<576, 256, 0, stream>>>(x, a_vals, p_vals, ws);
        // 128 mt x 8 ct-pairs = 1024 blocks; 4 waves each (2 ct x 2 D-half)
        hmlr_main_split<true><<<1024, 256, 0, stream>>>(x, ws, out);
    } else {
        hmlr_prep<false><<<64, 256, 0, stream>>>(x, a_vals, p_vals, ws);
        hmlr_main_split<false><<<1024, 256, 0, stream>>>(x, ws, out);
    }
}

// Round 9
// 15.335 us; speedup vs baseline: 1.4258x; 1.0527x over previous
//
#include <hip/hip_runtime.h>
#include <hip/hip_bf16.h>
#include <math.h>

// Problem constants (fixed by the reference setup_inputs)
#define NROWS 2048
#define KROWS 256
#define DDIM  512

typedef __attribute__((ext_vector_type(8))) short short8;
typedef __attribute__((ext_vector_type(4))) short short4v;
typedef __attribute__((ext_vector_type(4))) float f32x4;

// Workspace layout (bytes) — bf16 P/A stored in MFMA-fragment order:
//   chunk index ((tile*16 + s)*64 + kg*16 + r) holds
//   T[tile*16 + r][s*32 + kg*8 .. +8] as short8, so a wave load at
//   base + s*64chunks + lane is 1KB coalesced and fragment-ready.
//   PT [K/16][16][64] short8 : @0        (262144 B)
//   AT [K/16][16][64] short8 : @262144   (262144 B)
//   SC [K] float4            : @524288   (4096 B)   {p2, pa, na, kc}
#define AB_BYTE   262144
#define SC_FOFF   131072   // float offset

__device__ inline unsigned short f2bf(float f) {
    // round-to-nearest-even fp32 -> bf16 (inputs are finite)
    unsigned u = __float_as_uint(f);
    u += 0x7fffu + ((u >> 16) & 1u);
    return (unsigned short)(u >> 16);
}

__device__ inline float wave_reduce_sum(float v) {
    #pragma unroll
    for (int off = 32; off > 0; off >>= 1)
        v += __shfl_xor(v, off, 64);
    return v;
}

// Slim prep: 64 blocks x 256 threads, one k per wave.
// expmap0 + conformal prep -> bf16 P/A in fragment order + SC scalars.
__global__ __launch_bounds__(256) void hmlr_prep(
        const float* __restrict__ a_vals,
        const float* __restrict__ p_vals,
        float* __restrict__ ws) {
    const int tid  = threadIdx.x;
    const int w    = tid >> 6;
    const int lane = tid & 63;
    const int k    = blockIdx.x * 4 + w;  // 0..255

    const float4* pv4 = (const float4*)(p_vals) + k * (DDIM / 4) + lane * 2;
    const float4* av4 = (const float4*)(a_vals) + k * (DDIM / 4) + lane * 2;
    float4 p0 = pv4[0], p1 = pv4[1];
    float4 a0 = av4[0], a1 = av4[1];

    float pn2 = p0.x*p0.x + p0.y*p0.y + p0.z*p0.z + p0.w*p0.w
              + p1.x*p1.x + p1.y*p1.y + p1.z*p1.z + p1.w*p1.w;
    float an2 = a0.x*a0.x + a0.y*a0.y + a0.z*a0.z + a0.w*a0.w
              + a1.x*a1.x + a1.y*a1.y + a1.z*a1.z + a1.w*a1.w;
    float pa0 = p0.x*a0.x + p0.y*a0.y + p0.z*a0.z + p0.w*a0.w
              + p1.x*a1.x + p1.y*a1.y + p1.z*a1.z + p1.w*a1.w;

    pn2 = wave_reduce_sum(pn2);
    an2 = wave_reduce_sum(an2);
    pa0 = wave_reduce_sum(pa0);

    // expmap0 with c = 1: p = tanh(clamp(||u||,15)) * u / ||u||
    float u     = fmaxf(sqrtf(pn2), 1e-5f);
    float t     = tanhf(fminf(u, 15.0f));
    float scale = t / u;
    float p2    = scale * scale * pn2;       // ||p_poincare||^2
    float conf  = 1.0f - p2;                 // conformal factor (c=1)
    float na    = fmaxf(conf * sqrtf(an2), 1e-7f);  // max(||a_poincare||, 1e-7)
    float pa    = scale * conf * pa0;        // dot(p_poincare, a_poincare)
    float lam   = 2.0f / (1.0f - fminf(p2, 0.9999f)); // 1/c - 1e-4 = 0.9999
    float kc    = lam * na;                  // / sqrt(c) = 1

    float pf[8] = { scale*p0.x, scale*p0.y, scale*p0.z, scale*p0.w,
                    scale*p1.x, scale*p1.y, scale*p1.z, scale*p1.w };
    float af[8] = { conf*a0.x, conf*a0.y, conf*a0.z, conf*a0.w,
                    conf*a1.x, conf*a1.y, conf*a1.z, conf*a1.w };
    short8 pu, au;
    #pragma unroll
    for (int j = 0; j < 8; ++j) {
        pu[j] = (short)f2bf(pf[j]);
        au[j] = (short)f2bf(af[j]);
    }
    // fragment-order scatter: s = lane>>2, kg = lane&3, r = k&15
    short8* PT8 = (short8*)ws;
    short8* AT8 = (short8*)((char*)ws + AB_BYTE);
    const int ci = (((k >> 4) * 16 + (lane >> 2)) * 64) + (lane & 3) * 16 + (k & 15);
    PT8[ci] = pu;
    AT8[ci] = au;
    if (lane == 0)
        ((float4*)(ws + SC_FOFF))[k] = make_float4(p2, pa, na, kc);
}

// Main MFMA kernel: block = 1 mt x 4 ct (one wave each). X tile (16 rows x
// 512 cols fp32 = 32KB) is cooperatively loaded with dense coalesced float4
// loads, converted to bf16 fragment order in LDS (16KB) and y2 computed via
// 16-lane shfl reduce — no XT workspace round-trip, no 512-block prep pass.
// P/A global fragment preloads are issued BEFORE staging so they overlap it.
// C/D: col = lane&15 (class), row = (lane>>4)*4 + reg (m)   [m89 verified]
__global__ __launch_bounds__(256, 2) void hmlr_main(
        const float* __restrict__ x,
        const float* __restrict__ ws,
        float* __restrict__ out) {
    __shared__ short8 XS[16][64];   // 16KB bf16 X tile, fragment order
    __shared__ float  Y2S[16];

    const int tid  = threadIdx.x;
    const int lane = tid & 63;
    const int w    = tid >> 6;
    const int mt   = blockIdx.x >> 2;           // 0..127
    const int ct   = (blockIdx.x & 3) * 4 + w;  // 0..15
    const int m0   = mt * 16;
    const int c0   = ct * 16;
    const int row  = lane & 15;
    const int kg   = lane >> 4;

    const short8* PT8 = (const short8*)ws;
    const short8* AT8 = (const short8*)((const char*)ws + AB_BYTE);
    const float*  SC  = ws + SC_FOFF;

    // ---- issue P/A fragment preloads (overlap with X staging) ----
    const short8* pt = PT8 + ct * 16 * 64 + lane;
    const short8* at = AT8 + ct * 16 * 64 + lane;
    short8 pv[16], av[16];
    #pragma unroll
    for (int s = 0; s < 16; ++s) pv[s] = pt[s * 64];
    #pragma unroll
    for (int s = 0; s < 16; ++s) av[s] = at[s * 64];

    // ---- cooperative X staging: fp32 -> bf16 fragment-order LDS + y2 ----
    // thread t: row r = t>>4, within-row thread j = t&15;
    // reads float4 at cols j*4 + q*64 (q = 0..7) -> dense 256B per 16 lanes.
    {
        const int r = tid >> 4;
        const int j = tid & 15;
        const float* xrow = x + (m0 + r) * DDIM;
        float ss = 0.0f;
        #pragma unroll
        for (int q = 0; q < 8; ++q) {
            float4 v = *(const float4*)(xrow + j * 4 + q * 64);
            ss += v.x*v.x + v.y*v.y + v.z*v.z + v.w*v.w;
            // c = q*64 + j*4 -> s = 2q + (j>>3), kg = (j>>1)&3, e = (j&1)*4
            const int sfr = 2 * q + (j >> 3);
            const int kfr = (j >> 1) & 3;
            short4v h;
            h[0] = (short)f2bf(v.x); h[1] = (short)f2bf(v.y);
            h[2] = (short)f2bf(v.z); h[3] = (short)f2bf(v.w);
            *(short4v*)((unsigned short*)&XS[sfr][kfr * 16 + r] + (j & 1) * 4) = h;
        }
        // row-sum over the 16 lanes of this row (lanes (r&3)*16 + j)
        #pragma unroll
        for (int off = 1; off < 16; off <<= 1)
            ss += __shfl_xor(ss, off, 64);
        if (j == 0) Y2S[r] = ss;
    }
    __syncthreads();

    // ---- X fragments from LDS (consecutive b128, conflict-free) ----
    short8 xv[16];
    #pragma unroll
    for (int s = 0; s < 16; ++s) xv[s] = XS[s][lane];

    // ---- MFMA burst: 4 independent chains of depth 8 ----
    f32x4 aP[2] = {{0.f,0.f,0.f,0.f},{0.f,0.f,0.f,0.f}};
    f32x4 aA[2] = {{0.f,0.f,0.f,0.f},{0.f,0.f,0.f,0.f}};
    #pragma unroll
    for (int s = 0; s < 16; ++s) {
        aP[s & 1] = __builtin_amdgcn_mfma_f32_16x16x32_bf16(xv[s], pv[s], aP[s & 1], 0, 0, 0);
        aA[s & 1] = __builtin_amdgcn_mfma_f32_16x16x32_bf16(xv[s], av[s], aA[s & 1], 0, 0, 0);
    }
    f32x4 accP = aP[0] + aP[1];
    f32x4 accA = aA[0] + aA[1];

    // ---- fused epilogue ----
    const int c = c0 + row;
    f32x4 sc = *(const f32x4*)(SC + 4 * c);
    const float p2 = sc[0], pa = sc[1], na = sc[2], kc = sc[3];
    #pragma unroll
    for (int j = 0; j < 4; ++j) {
        const int m     = m0 + kg * 4 + j;
        const float y2n = Y2S[kg * 4 + j];
        const float xpv = accP[j];
        const float xav = accA[j];
        // mobius_addition_batch(-p, x): xy = -xp
        const float alpha = 1.0f - 2.0f * xpv + y2n;       // 1 + 2c*xy + c*y2
        const float beta  = 1.0f - p2;                     // 1 - c*||p||^2
        const float gam   = 1.0f - 2.0f * xpv + p2 * y2n;  // denom
        const float gi    = __builtin_amdgcn_rcpf(gam + 1e-5f);
        const float num   = 2.0f * (beta * xav - alpha * pa) * gi;
        const float mob2  = (alpha*alpha*p2 + beta*beta*y2n
                             - 2.0f*alpha*beta*xpv) * gi * gi;
        const float den   = na * (1.0f - mob2);
        const float z     = num * __builtin_amdgcn_rcpf(den);
        // arsinh(z) = log(max(z + sqrt(1+z^2), 1e-5))
        const float arg   = fmaxf(z + __builtin_amdgcn_sqrtf(1.0f + z * z), 1e-5f);
        out[m * KROWS + c] = kc * __logf(arg);
    }
}

extern "C" void kernel_launch(void* const* d_in, const int* in_sizes, int n_in,
                              void* d_out, int out_size, void* d_ws, size_t ws_size,
                              hipStream_t stream) {
    (void)in_sizes; (void)n_in; (void)out_size; (void)ws_size;
    const float* x      = (const float*)d_in[0];
    const float* a_vals = (const float*)d_in[1];
    const float* p_vals = (const float*)d_in[2];
    float* ws  = (float*)d_ws;
    float* out = (float*)d_out;

    // prep: 64 blocks (one k per wave) — P/A/SC only, single dispatch round
    hmlr_prep<<<64, 256, 0, stream>>>(a_vals, p_vals, ws);
    // main: 128 mt x 4 ct-groups = 512 blocks, self-contained X staging
    hmlr_main<<<512, 256, 0, stream>>>(x, ws, out);
}